// Round 9
// baseline (224.889 us; speedup 1.0000x reference)
//
#include <hip/hip_runtime.h>
#include <hip/hip_fp16.h>
#include <math.h>

#define N_NODES    100000
#define N_EDGES    3200000
#define NUM_GRAPHS 512
#define D_IN       7
#define D_H        16
#define D_H2       8                           // half2 words per node row
#define SHIFT      7
#define BWIDTH     128                         // cols per bucket
#define NB         782                         // ceil(N_NODES / BWIDTH)
#define CHUNK      2048
#define NCH        1563                        // ceil(N_EDGES / CHUNK)
#define PC         7                           // ceil(NCH / 256)
#define PB         4                           // ceil(NB / 256) buckets per thread

// ---- pass A: per-chunk bucket histograms. cnt[chunk][bucket], coalesced rows ----
__global__ void hist_kernel(const int* __restrict__ col, int* __restrict__ cnt) {
    __shared__ int lh[NB];
    int tid = threadIdx.x;
    for (int i = tid; i < NB; i += blockDim.x) lh[i] = 0;
    __syncthreads();
    int e0 = blockIdx.x * CHUNK;
    int e1 = e0 + CHUNK; if (e1 > N_EDGES) e1 = N_EDGES;
    for (int e = e0 + tid; e < e1; e += blockDim.x)
        atomicAdd(&lh[col[e] >> SHIFT], 1);
    __syncthreads();
    int* outp = cnt + (size_t)blockIdx.x * NB;
    for (int i = tid; i < NB; i += blockDim.x) outp[i] = lh[i];
}

// ---- pass B: per-bucket exclusive scan over chunks ----
__global__ void colscan_kernel(const int* __restrict__ cnt, int* __restrict__ base,
                               int* __restrict__ bcnt) {
    __shared__ int ts[256];
    int b = blockIdx.x;
    int tid = threadIdx.x;
    int c0 = tid * PC;
    int vals[PC];
    int sum = 0;
#pragma unroll
    for (int q = 0; q < PC; ++q) {
        int c = c0 + q;
        int v = (c < NCH) ? cnt[(size_t)c * NB + b] : 0;
        vals[q] = v; sum += v;
    }
    ts[tid] = sum;
    __syncthreads();
    for (int st = 1; st < 256; st <<= 1) {
        int v = (tid >= st) ? ts[tid - st] : 0;
        __syncthreads();
        ts[tid] += v;
        __syncthreads();
    }
    int run = ts[tid] - sum;
    int* bp = base + (size_t)b * NCH;
#pragma unroll
    for (int q = 0; q < PC; ++q) {
        int c = c0 + q;
        if (c < NCH) { bp[c] = run; run += vals[q]; }
    }
    if (tid == 0) bcnt[b] = ts[255];
}

// ---- pass C: exclusive scan of bucket totals -> offs (single block) ----
__global__ void scan_kernel(const int* __restrict__ bcnt, int* __restrict__ offs) {
    __shared__ int lds[1024];
    int tid = threadIdx.x;
    lds[tid] = (tid < NB) ? bcnt[tid] : 0;
    __syncthreads();
    for (int st = 1; st < 1024; st <<= 1) {
        int v = (tid >= st) ? lds[tid - st] : 0;
        __syncthreads();
        lds[tid] += v;
        __syncthreads();
    }
    if (tid < NB) offs[tid + 1] = lds[tid];
    if (tid == 0) offs[0] = 0;
}

// ---- pass D: place with LDS staging + precomputed destinations + coalesced flush ----
__global__ void place_kernel(const int* __restrict__ row, const int* __restrict__ col,
                             const int* __restrict__ base, const int* __restrict__ offs,
                             int* __restrict__ part) {
    __shared__ int lh[NB];
    __shared__ int sc[NB];
    __shared__ int lb[NB];
    __shared__ int ts[256];
    __shared__ int stage[CHUNK];
    __shared__ int dstv[CHUNK];

    int c = blockIdx.x;
    int tid = threadIdx.x;
    int e0 = c * CHUNK;
    int e1 = e0 + CHUNK; if (e1 > N_EDGES) e1 = N_EDGES;
    int n  = e1 - e0;

    for (int i = tid; i < NB; i += blockDim.x) lh[i] = 0;
    __syncthreads();
    for (int e = e0 + tid; e < e1; e += blockDim.x)
        atomicAdd(&lh[col[e] >> SHIFT], 1);
    __syncthreads();
    int b0 = tid * PB;
    int vals[PB];
    int sum = 0;
#pragma unroll
    for (int q = 0; q < PB; ++q) {
        int b = b0 + q;
        int v = (b < NB) ? lh[b] : 0;
        vals[q] = v; sum += v;
    }
    ts[tid] = sum;
    __syncthreads();
    for (int st = 1; st < 256; st <<= 1) {
        int v = (tid >= st) ? ts[tid - st] : 0;
        __syncthreads();
        ts[tid] += v;
        __syncthreads();
    }
    int run = ts[tid] - sum;
#pragma unroll
    for (int q = 0; q < PB; ++q) {
        int b = b0 + q;
        if (b < NB) {
            sc[b] = run;
            lb[b] = offs[b] + base[(size_t)b * NCH + c];
            run += vals[q];
            lh[b] = 0;
        }
    }
    __syncthreads();
    for (int e = e0 + tid; e < e1; e += blockDim.x) {
        int cc = col[e];
        int b = cc >> SHIFT;
        int rank = atomicAdd(&lh[b], 1);
        int loc = sc[b] + rank;
        stage[loc] = (row[e] << SHIFT) | (cc & (BWIDTH - 1));
        dstv[loc]  = lb[b] + rank;
    }
    __syncthreads();
    for (int i = tid; i < n; i += blockDim.x)
        part[dstv[i]] = stage[i];
}

// ---- pass E: per-bucket CSR build + node_off/deg/dinv ----
__global__ void csr_kernel(const int* __restrict__ part, const int* __restrict__ offs,
                           int* __restrict__ csr, int* __restrict__ node_off,
                           int* __restrict__ deg, float* __restrict__ dinv) {
    __shared__ int cnt[BWIDTH];
    __shared__ int scn[BWIDTH];
    __shared__ int cur[BWIDTH];
    int b = blockIdx.x;
    int o0 = offs[b], o1 = offs[b + 1];
    if (threadIdx.x < BWIDTH) cnt[threadIdx.x] = 0;
    __syncthreads();
    for (int j = o0 + threadIdx.x; j < o1; j += blockDim.x)
        atomicAdd(&cnt[part[j] & (BWIDTH - 1)], 1);
    __syncthreads();
    if (threadIdx.x < BWIDTH) scn[threadIdx.x] = cnt[threadIdx.x];
    __syncthreads();
    for (int st = 1; st < BWIDTH; st <<= 1) {
        int v = 0;
        if (threadIdx.x < BWIDTH && threadIdx.x >= st) v = scn[threadIdx.x - st];
        __syncthreads();
        if (threadIdx.x < BWIDTH) scn[threadIdx.x] += v;
        __syncthreads();
    }
    if (threadIdx.x < BWIDTH) {
        int excl = scn[threadIdx.x] - cnt[threadIdx.x];
        cur[threadIdx.x] = excl;
        int c = b * BWIDTH + threadIdx.x;
        if (c < N_NODES) {
            node_off[c] = o0 + excl;
            deg[c] = cnt[threadIdx.x];
            dinv[c] = rsqrtf((float)cnt[threadIdx.x] + 1.0f);   // +1 self-loop
        }
    }
    __syncthreads();
    for (int j = o0 + threadIdx.x; j < o1; j += blockDim.x) {
        int e = part[j];
        int l = e & (BWIDTH - 1);
        int pos = atomicAdd(&cur[l], 1);
        csr[o0 + pos] = e >> SHIFT;
    }
}

// s[v,:] = dinv[v] * (x[v,:] @ W1), packed half2 (8 words/node)
__global__ void xw1_kernel(const float* __restrict__ x, const float* __restrict__ W1,
                           const float* __restrict__ dinv, unsigned* __restrict__ sh) {
    int v = blockIdx.x * blockDim.x + threadIdx.x;
    if (v >= N_NODES) return;
    float xv[D_IN];
#pragma unroll
    for (int j = 0; j < D_IN; ++j) xv[j] = x[v * D_IN + j];
    float dv = dinv[v];
#pragma unroll
    for (int k2 = 0; k2 < D_H2; ++k2) {
        float a0 = 0.f, a1 = 0.f;
#pragma unroll
        for (int j = 0; j < D_IN; ++j) {
            a0 += xv[j] * W1[j * D_H + 2 * k2];
            a1 += xv[j] * W1[j * D_H + 2 * k2 + 1];
        }
        __half2 p = __floats2half2_rn(a0 * dv, a1 * dv);
        sh[v * D_H2 + k2] = *(unsigned*)&p;
    }
}

// layer-1 pull: 8 edge-slots x 8 half2-lanes, 4 gathers in flight, barrier-free
// fused @W2 epilogue via intra-8-lane shuffles.
__global__ void pull1_kernel(const unsigned* __restrict__ sh, const int* __restrict__ csr,
                             const int* __restrict__ node_off, const int* __restrict__ deg,
                             const float* __restrict__ dinv, const float* __restrict__ b1,
                             const float* __restrict__ W2, unsigned* __restrict__ s2h) {
    int wave = threadIdx.x >> 6;
    int v = blockIdx.x * 4 + wave;
    int lane = threadIdx.x & 63;
    int es = lane >> 3;                 // 0..7 edge-slot
    int f  = lane & 7;                  // feature-pair
    int d  = deg[v];
    int o0 = node_off[v];
    float ax = 0.f, ay = 0.f;
    int j = es;
    for (; j + 24 < d; j += 32) {       // 4 gathers in flight; one iter covers 32 edges
        int r1 = __builtin_nontemporal_load(&csr[o0 + j]);
        int r2 = __builtin_nontemporal_load(&csr[o0 + j + 8]);
        int r3 = __builtin_nontemporal_load(&csr[o0 + j + 16]);
        int r4 = __builtin_nontemporal_load(&csr[o0 + j + 24]);
        unsigned w1 = sh[r1 * D_H2 + f], w2 = sh[r2 * D_H2 + f];
        unsigned w3 = sh[r3 * D_H2 + f], w4 = sh[r4 * D_H2 + f];
        __half2 p1 = *(__half2*)&w1, p2 = *(__half2*)&w2;
        __half2 p3 = *(__half2*)&w3, p4 = *(__half2*)&w4;
        ax += (__low2float(p1) + __low2float(p2)) + (__low2float(p3) + __low2float(p4));
        ay += (__high2float(p1) + __high2float(p2)) + (__high2float(p3) + __high2float(p4));
    }
    for (; j < d; j += 8) {
        int r = __builtin_nontemporal_load(&csr[o0 + j]);
        unsigned w = sh[r * D_H2 + f];
        __half2 p = *(__half2*)&w;
        ax += __low2float(p);
        ay += __high2float(p);
    }
    ax += __shfl_xor(ax, 8, 64);  ay += __shfl_xor(ay, 8, 64);
    ax += __shfl_xor(ax, 16, 64); ay += __shfl_xor(ay, 16, 64);
    ax += __shfl_xor(ax, 32, 64); ay += __shfl_xor(ay, 32, 64);
    // all lanes now hold the sums for feature-pair f
    float dv = dinv[v];
    unsigned ws = sh[v * D_H2 + f];
    __half2 ps = *(__half2*)&ws;
    float h0 = fmaxf(dv * (ax + __low2float(ps)) + b1[2 * f], 0.f);
    float h1 = fmaxf(dv * (ay + __high2float(ps)) + b1[2 * f + 1], 0.f);
    // each 8-lane group holds the full h-row across f=0..7
    int base = lane & 0x38;
    float a0 = 0.f, a1 = 0.f;
#pragma unroll
    for (int jj = 0; jj < D_H2; ++jj) {
        float hj0 = __shfl(h0, base | jj, 64);   // h[v, 2jj]
        float hj1 = __shfl(h1, base | jj, 64);   // h[v, 2jj+1]
        a0 += hj0 * W2[(2 * jj) * D_H + 2 * f] + hj1 * W2[(2 * jj + 1) * D_H + 2 * f];
        a1 += hj0 * W2[(2 * jj) * D_H + 2 * f + 1] + hj1 * W2[(2 * jj + 1) * D_H + 2 * f + 1];
    }
    if (es == 0) {
        __half2 p = __floats2half2_rn(a0 * dv, a1 * dv);
        s2h[v * D_H2 + f] = *(unsigned*)&p;
    }
}

// layer-2 pull: h2 = relu(dinv*(gather+self)+b2), fp32 float2 out, barrier-free
__global__ void pull2_kernel(const unsigned* __restrict__ sh, const int* __restrict__ csr,
                             const int* __restrict__ node_off, const int* __restrict__ deg,
                             const float* __restrict__ dinv, const float* __restrict__ b2,
                             float2* __restrict__ h2) {
    int wave = threadIdx.x >> 6;
    int v = blockIdx.x * 4 + wave;
    int lane = threadIdx.x & 63;
    int es = lane >> 3;
    int f  = lane & 7;
    int d  = deg[v];
    int o0 = node_off[v];
    float ax = 0.f, ay = 0.f;
    int j = es;
    for (; j + 24 < d; j += 32) {
        int r1 = __builtin_nontemporal_load(&csr[o0 + j]);
        int r2 = __builtin_nontemporal_load(&csr[o0 + j + 8]);
        int r3 = __builtin_nontemporal_load(&csr[o0 + j + 16]);
        int r4 = __builtin_nontemporal_load(&csr[o0 + j + 24]);
        unsigned w1 = sh[r1 * D_H2 + f], w2 = sh[r2 * D_H2 + f];
        unsigned w3 = sh[r3 * D_H2 + f], w4 = sh[r4 * D_H2 + f];
        __half2 p1 = *(__half2*)&w1, p2 = *(__half2*)&w2;
        __half2 p3 = *(__half2*)&w3, p4 = *(__half2*)&w4;
        ax += (__low2float(p1) + __low2float(p2)) + (__low2float(p3) + __low2float(p4));
        ay += (__high2float(p1) + __high2float(p2)) + (__high2float(p3) + __high2float(p4));
    }
    for (; j < d; j += 8) {
        int r = __builtin_nontemporal_load(&csr[o0 + j]);
        unsigned w = sh[r * D_H2 + f];
        __half2 p = *(__half2*)&w;
        ax += __low2float(p);
        ay += __high2float(p);
    }
    ax += __shfl_xor(ax, 8, 64);  ay += __shfl_xor(ay, 8, 64);
    ax += __shfl_xor(ax, 16, 64); ay += __shfl_xor(ay, 16, 64);
    ax += __shfl_xor(ax, 32, 64); ay += __shfl_xor(ay, 32, 64);
    if (es == 0) {
        float dv = dinv[v];
        unsigned ws = sh[v * D_H2 + f];
        __half2 ps = *(__half2*)&ws;
        float2 o;
        o.x = fmaxf(dv * (ax + __low2float(ps)) + b2[2 * f], 0.f);
        o.y = fmaxf(dv * (ay + __high2float(ps)) + b2[2 * f + 1], 0.f);
        h2[v * D_H2 + f] = o;
    }
}

// batch sorted: starts[g] = first node of graph g; starts[NUM_GRAPHS] = N
__global__ void starts_kernel(const int* __restrict__ batch, int* __restrict__ starts) {
    int v = blockIdx.x * blockDim.x + threadIdx.x;
    if (v >= N_NODES) return;
    int bv = batch[v];
    int prev = (v == 0) ? -1 : batch[v - 1];
    for (int g = prev + 1; g <= bv; ++g) starts[g] = v;
    if (v == N_NODES - 1) {
        for (int g = bv + 1; g <= NUM_GRAPHS; ++g) starts[g] = N_NODES;
    }
}

// one block per graph: mean-pool h rows then sigmoid(pool @ Wl + bl)
__global__ void pool_head_kernel(const float* __restrict__ h, const int* __restrict__ starts,
                                 const float* __restrict__ Wl, const float* __restrict__ bl,
                                 float* __restrict__ out) {
    int g = blockIdx.x;
    int v0 = starts[g], v1 = starts[g + 1];
    int k = threadIdx.x & 15;
    int vi = threadIdx.x >> 4;
    float acc = 0.f;
    for (int v = v0 + vi; v < v1; v += 16) acc += h[v * D_H + k];
    acc += __shfl_xor(acc, 16, 64);
    acc += __shfl_xor(acc, 32, 64);
    __shared__ float sm[4][D_H];
    int lane = threadIdx.x & 63;
    if (lane < 16) sm[threadIdx.x >> 6][k] = acc;
    __syncthreads();
    if (threadIdx.x < 16) {
        float tot = sm[0][k] + sm[1][k] + sm[2][k] + sm[3][k];
        float cntf = (float)(v1 - v0);
        tot /= fmaxf(cntf, 1.0f);
        float p = tot * Wl[k];
        p += __shfl_xor(p, 1, 64);
        p += __shfl_xor(p, 2, 64);
        p += __shfl_xor(p, 4, 64);
        p += __shfl_xor(p, 8, 64);
        if (k == 0) out[g] = 1.0f / (1.0f + expf(-(p + bl[0])));
    }
}

// ---------------- launch ----------------

extern "C" void kernel_launch(void* const* d_in, const int* in_sizes, int n_in,
                              void* d_out, int out_size, void* d_ws, size_t ws_size,
                              hipStream_t stream) {
    const float* x     = (const float*)d_in[0];
    const int*   ei    = (const int*)d_in[1];   // [2, E]: row then col
    const int*   batch = (const int*)d_in[2];
    const float* W1    = (const float*)d_in[3];
    const float* b1    = (const float*)d_in[4];
    const float* W2    = (const float*)d_in[5];
    const float* b2    = (const float*)d_in[6];
    const float* Wl    = (const float*)d_in[7];
    const float* bl    = (const float*)d_in[8];
    float* out = (float*)d_out;

    const int* row = ei;
    const int* col = ei + N_EDGES;

    // workspace layout. Region A is time-shared: {cnt+base} then csr.
    char* wsb = (char*)d_ws;
    size_t o = 0;
    int*      part     = (int*)(wsb + o);      o += (size_t)N_EDGES * 4;      // 12.8 MB
    char*     regionA  = wsb + o;              o += (size_t)N_EDGES * 4;      // 12.8 MB
    int*      cnt      = (int*)regionA;                                       // [NCH][NB]
    int*      base     = (int*)(regionA + (size_t)NCH * NB * 4);              // [NB][NCH]
    int*      csr      = (int*)regionA;                                       // after place
    int*      bcnt     = (int*)(wsb + o);      o += 1024 * 4;
    int*      offs     = (int*)(wsb + o);      o += 1024 * 4;
    int*      node_off = (int*)(wsb + o);      o += 100352 * 4;
    int*      deg      = (int*)(wsb + o);      o += 100352 * 4;
    float*    dinv     = (float*)(wsb + o);    o += 100352 * 4;
    unsigned* sAh      = (unsigned*)(wsb + o); o += (size_t)N_NODES * D_H2 * 4; // 3.2 MB
    unsigned* sBh      = (unsigned*)(wsb + o); o += (size_t)N_NODES * D_H2 * 4; // 3.2 MB
    float*    h2       = (float*)(wsb + o);    o += (size_t)N_NODES * D_H * 4;  // 6.4 MB
    int*      starts   = (int*)(wsb + o);      o += 1024 * 4;

    const int B = 256;
    const int NVB = (N_NODES + B - 1) / B;   // 391

    // ---- build CSR via deterministic two-level scan (no global cursor atomics) ----
    hist_kernel<<<NCH, B, 0, stream>>>(col, cnt);
    colscan_kernel<<<NB, B, 0, stream>>>(cnt, base, bcnt);
    scan_kernel<<<1, 1024, 0, stream>>>(bcnt, offs);
    place_kernel<<<NCH, B, 0, stream>>>(row, col, base, offs, part);
    csr_kernel<<<NB, B, 0, stream>>>(part, offs, csr, node_off, deg, dinv);

    // ---- layer 1 (+ fused layer-2 GEMM) ----
    xw1_kernel<<<NVB, B, 0, stream>>>(x, W1, dinv, sAh);
    pull1_kernel<<<N_NODES / 4, B, 0, stream>>>(sAh, csr, node_off, deg, dinv,
                                                b1, W2, sBh);
    // ---- layer 2 ----
    pull2_kernel<<<N_NODES / 4, B, 0, stream>>>(sBh, csr, node_off, deg, dinv,
                                                b2, (float2*)h2);
    // ---- pool + head ----
    starts_kernel<<<NVB, B, 0, stream>>>(batch, starts);
    pool_head_kernel<<<NUM_GRAPHS, B, 0, stream>>>(h2, starts, Wl, bl, out);
}

// Round 10
// 170.382 us; speedup vs baseline: 1.3199x; 1.3199x over previous
//
#include <hip/hip_runtime.h>
#include <hip/hip_fp16.h>
#include <math.h>

#define N_NODES    100000
#define N_EDGES    3200000
#define NUM_GRAPHS 512
#define D_IN       7
#define D_H        16
#define D_H2       8                           // half2 words per node row
#define SHIFT      7
#define BWIDTH     128                         // cols per bucket
#define NB         782                         // ceil(N_NODES / BWIDTH)
#define CHUNK      2048
#define NCH        1563                        // ceil(N_EDGES / CHUNK)
#define PC         7                           // ceil(NCH / 256)
#define PB         4                           // ceil(NB / 256) buckets per thread
#define LSTRIDE    10                          // u32 words per staged LDS row (40B)

// ---- pass A: per-chunk bucket histograms ----
__global__ void hist_kernel(const int* __restrict__ col, int* __restrict__ cnt) {
    __shared__ int lh[NB];
    int tid = threadIdx.x;
    for (int i = tid; i < NB; i += blockDim.x) lh[i] = 0;
    __syncthreads();
    int e0 = blockIdx.x * CHUNK;
    int e1 = e0 + CHUNK; if (e1 > N_EDGES) e1 = N_EDGES;
    for (int e = e0 + tid; e < e1; e += blockDim.x)
        atomicAdd(&lh[col[e] >> SHIFT], 1);
    __syncthreads();
    int* outp = cnt + (size_t)blockIdx.x * NB;
    for (int i = tid; i < NB; i += blockDim.x) outp[i] = lh[i];
}

// ---- pass B: per-bucket exclusive scan over chunks ----
__global__ void colscan_kernel(const int* __restrict__ cnt, int* __restrict__ base,
                               int* __restrict__ bcnt) {
    __shared__ int ts[256];
    int b = blockIdx.x;
    int tid = threadIdx.x;
    int c0 = tid * PC;
    int vals[PC];
    int sum = 0;
#pragma unroll
    for (int q = 0; q < PC; ++q) {
        int c = c0 + q;
        int v = (c < NCH) ? cnt[(size_t)c * NB + b] : 0;
        vals[q] = v; sum += v;
    }
    ts[tid] = sum;
    __syncthreads();
    for (int st = 1; st < 256; st <<= 1) {
        int v = (tid >= st) ? ts[tid - st] : 0;
        __syncthreads();
        ts[tid] += v;
        __syncthreads();
    }
    int run = ts[tid] - sum;
    int* bp = base + (size_t)b * NCH;
#pragma unroll
    for (int q = 0; q < PC; ++q) {
        int c = c0 + q;
        if (c < NCH) { bp[c] = run; run += vals[q]; }
    }
    if (tid == 0) bcnt[b] = ts[255];
}

// ---- pass C: exclusive scan of bucket totals -> offs ----
__global__ void scan_kernel(const int* __restrict__ bcnt, int* __restrict__ offs) {
    __shared__ int lds[1024];
    int tid = threadIdx.x;
    lds[tid] = (tid < NB) ? bcnt[tid] : 0;
    __syncthreads();
    for (int st = 1; st < 1024; st <<= 1) {
        int v = (tid >= st) ? lds[tid - st] : 0;
        __syncthreads();
        lds[tid] += v;
        __syncthreads();
    }
    if (tid < NB) offs[tid + 1] = lds[tid];
    if (tid == 0) offs[0] = 0;
}

// ---- pass D: place with LDS staging + precomputed destinations + coalesced flush ----
__global__ void place_kernel(const int* __restrict__ row, const int* __restrict__ col,
                             const int* __restrict__ base, const int* __restrict__ offs,
                             int* __restrict__ part) {
    __shared__ int lh[NB];
    __shared__ int sc[NB];
    __shared__ int lb[NB];
    __shared__ int ts[256];
    __shared__ int stage[CHUNK];
    __shared__ int dstv[CHUNK];

    int c = blockIdx.x;
    int tid = threadIdx.x;
    int e0 = c * CHUNK;
    int e1 = e0 + CHUNK; if (e1 > N_EDGES) e1 = N_EDGES;
    int n  = e1 - e0;

    for (int i = tid; i < NB; i += blockDim.x) lh[i] = 0;
    __syncthreads();
    for (int e = e0 + tid; e < e1; e += blockDim.x)
        atomicAdd(&lh[col[e] >> SHIFT], 1);
    __syncthreads();
    int b0 = tid * PB;
    int vals[PB];
    int sum = 0;
#pragma unroll
    for (int q = 0; q < PB; ++q) {
        int b = b0 + q;
        int v = (b < NB) ? lh[b] : 0;
        vals[q] = v; sum += v;
    }
    ts[tid] = sum;
    __syncthreads();
    for (int st = 1; st < 256; st <<= 1) {
        int v = (tid >= st) ? ts[tid - st] : 0;
        __syncthreads();
        ts[tid] += v;
        __syncthreads();
    }
    int run = ts[tid] - sum;
#pragma unroll
    for (int q = 0; q < PB; ++q) {
        int b = b0 + q;
        if (b < NB) {
            sc[b] = run;
            lb[b] = offs[b] + base[(size_t)b * NCH + c];
            run += vals[q];
            lh[b] = 0;
        }
    }
    __syncthreads();
    for (int e = e0 + tid; e < e1; e += blockDim.x) {
        int cc = col[e];
        int b = cc >> SHIFT;
        int rank = atomicAdd(&lh[b], 1);
        int loc = sc[b] + rank;
        stage[loc] = (row[e] << SHIFT) | (cc & (BWIDTH - 1));
        dstv[loc]  = lb[b] + rank;
    }
    __syncthreads();
    for (int i = tid; i < n; i += blockDim.x)
        part[dstv[i]] = stage[i];
}

// ---- pass E: per-bucket CSR build + node_off/deg/dinv ----
__global__ void csr_kernel(const int* __restrict__ part, const int* __restrict__ offs,
                           int* __restrict__ csr, int* __restrict__ node_off,
                           int* __restrict__ deg, float* __restrict__ dinv) {
    __shared__ int cnt[BWIDTH];
    __shared__ int scn[BWIDTH];
    __shared__ int cur[BWIDTH];
    int b = blockIdx.x;
    int o0 = offs[b], o1 = offs[b + 1];
    if (threadIdx.x < BWIDTH) cnt[threadIdx.x] = 0;
    __syncthreads();
    for (int j = o0 + threadIdx.x; j < o1; j += blockDim.x)
        atomicAdd(&cnt[part[j] & (BWIDTH - 1)], 1);
    __syncthreads();
    if (threadIdx.x < BWIDTH) scn[threadIdx.x] = cnt[threadIdx.x];
    __syncthreads();
    for (int st = 1; st < BWIDTH; st <<= 1) {
        int v = 0;
        if (threadIdx.x < BWIDTH && threadIdx.x >= st) v = scn[threadIdx.x - st];
        __syncthreads();
        if (threadIdx.x < BWIDTH) scn[threadIdx.x] += v;
        __syncthreads();
    }
    if (threadIdx.x < BWIDTH) {
        int excl = scn[threadIdx.x] - cnt[threadIdx.x];
        cur[threadIdx.x] = excl;
        int c = b * BWIDTH + threadIdx.x;
        if (c < N_NODES) {
            node_off[c] = o0 + excl;
            deg[c] = cnt[threadIdx.x];
            dinv[c] = rsqrtf((float)cnt[threadIdx.x] + 1.0f);   // +1 self-loop
        }
    }
    __syncthreads();
    for (int j = o0 + threadIdx.x; j < o1; j += blockDim.x) {
        int e = part[j];
        int l = e & (BWIDTH - 1);
        int pos = atomicAdd(&cur[l], 1);
        csr[o0 + pos] = e >> SHIFT;
    }
}

// s[v,:] = dinv[v] * (x[v,:] @ W1), packed half2 (8 words/node)
__global__ void xw1_kernel(const float* __restrict__ x, const float* __restrict__ W1,
                           const float* __restrict__ dinv, unsigned* __restrict__ sh) {
    int v = blockIdx.x * blockDim.x + threadIdx.x;
    if (v >= N_NODES) return;
    float xv[D_IN];
#pragma unroll
    for (int j = 0; j < D_IN; ++j) xv[j] = x[v * D_IN + j];
    float dv = dinv[v];
#pragma unroll
    for (int k2 = 0; k2 < D_H2; ++k2) {
        float a0 = 0.f, a1 = 0.f;
#pragma unroll
        for (int j = 0; j < D_IN; ++j) {
            a0 += xv[j] * W1[j * D_H + 2 * k2];
            a1 += xv[j] * W1[j * D_H + 2 * k2 + 1];
        }
        __half2 p = __floats2half2_rn(a0 * dv, a1 * dv);
        sh[v * D_H2 + k2] = *(unsigned*)&p;
    }
}

// ---- shared gather core: lane-per-edge, LDS transpose-reduce.
// Returns per-lane fp32 sum for feature k = lane&15 (replicated over g = lane>>4).
__device__ __forceinline__ float gather_sum(const unsigned* __restrict__ sh,
                                            const int* __restrict__ csr,
                                            int o0, int d, unsigned* st,
                                            int lane, int g, int k) {
    float acc = 0.f;
    int rdbase = g * 16 * LSTRIDE + (k >> 1);
    bool hi = (k & 1);
    for (int base = 0; base < d; base += 64) {
        int j = base + lane;
        uint2 wa = make_uint2(0u, 0u), wb = make_uint2(0u, 0u);
        uint2 wc = make_uint2(0u, 0u), wd = make_uint2(0u, 0u);
        if (j < d) {
            int r = csr[o0 + j];
            const uint4* p = (const uint4*)(sh + (size_t)r * D_H2);
            uint4 a = p[0];
            uint4 b = p[1];
            wa = make_uint2(a.x, a.y); wb = make_uint2(a.z, a.w);
            wc = make_uint2(b.x, b.y); wd = make_uint2(b.z, b.w);
        }
        // guard: previous pass's reads fully drained before overwriting rows
        asm volatile("s_waitcnt lgkmcnt(0)" ::: "memory");
        uint2* dst = (uint2*)(st + lane * LSTRIDE);
        dst[0] = wa; dst[1] = wb; dst[2] = wc; dst[3] = wd;
        asm volatile("s_waitcnt lgkmcnt(0)" ::: "memory");
#pragma unroll
        for (int i = 0; i < 16; ++i) {
            unsigned w = st[rdbase + i * LSTRIDE];
            __half2 p = *(__half2*)&w;
            acc += hi ? __high2float(p) : __low2float(p);
        }
    }
    acc += __shfl_xor(acc, 16, 64);
    acc += __shfl_xor(acc, 32, 64);
    return acc;
}

// layer-1 pull + fused @W2 epilogue (LDS-broadcast h-row)
__global__ void __launch_bounds__(256, 8)
pull1_kernel(const unsigned* __restrict__ sh, const int* __restrict__ csr,
             const int* __restrict__ node_off, const int* __restrict__ deg,
             const float* __restrict__ dinv, const float* __restrict__ b1,
             const float* __restrict__ W2, unsigned* __restrict__ s2h) {
    __shared__ unsigned stage[4][64 * LSTRIDE];   // 10240 B
    __shared__ float hrow[4][D_H];
    int wave = threadIdx.x >> 6;
    int v = blockIdx.x * 4 + wave;
    int lane = threadIdx.x & 63;
    int g = lane >> 4, k = lane & 15;
    float w2c[D_H];
#pragma unroll
    for (int j = 0; j < D_H; ++j) w2c[j] = W2[j * D_H + k];
    int d = deg[v], o0 = node_off[v];
    float acc = gather_sum(sh, csr, o0, d, stage[wave], lane, g, k);
    float dv = dinv[v];
    unsigned ws = sh[(size_t)v * D_H2 + (k >> 1)];
    __half2 ps = *(__half2*)&ws;
    float selfv = (k & 1) ? __high2float(ps) : __low2float(ps);
    float h = fmaxf(dv * (acc + selfv) + b1[k], 0.f);
    if (g == 0) hrow[wave][k] = h;
    asm volatile("s_waitcnt lgkmcnt(0)" ::: "memory");
    // broadcast-read full h row, dot with W2 column k
    const float4* hp = (const float4*)hrow[wave];
    float4 h0 = hp[0], h1 = hp[1], h2 = hp[2], h3 = hp[3];
    float a2 = h0.x * w2c[0] + h0.y * w2c[1] + h0.z * w2c[2] + h0.w * w2c[3]
             + h1.x * w2c[4] + h1.y * w2c[5] + h1.z * w2c[6] + h1.w * w2c[7]
             + h2.x * w2c[8] + h2.y * w2c[9] + h2.z * w2c[10] + h2.w * w2c[11]
             + h3.x * w2c[12] + h3.y * w2c[13] + h3.z * w2c[14] + h3.w * w2c[15];
    a2 *= dv;
    float a2hi = __shfl_xor(a2, 1, 64);
    if (g == 0 && (k & 1) == 0) {
        __half2 p = __floats2half2_rn(a2, a2hi);
        s2h[(size_t)v * D_H2 + (k >> 1)] = *(unsigned*)&p;
    }
}

// layer-2 pull: h2 = relu(dinv*(gather+self)+b2), fp32 out
__global__ void __launch_bounds__(256, 8)
pull2_kernel(const unsigned* __restrict__ sh, const int* __restrict__ csr,
             const int* __restrict__ node_off, const int* __restrict__ deg,
             const float* __restrict__ dinv, const float* __restrict__ b2,
             float* __restrict__ h2) {
    __shared__ unsigned stage[4][64 * LSTRIDE];
    int wave = threadIdx.x >> 6;
    int v = blockIdx.x * 4 + wave;
    int lane = threadIdx.x & 63;
    int g = lane >> 4, k = lane & 15;
    int d = deg[v], o0 = node_off[v];
    float acc = gather_sum(sh, csr, o0, d, stage[wave], lane, g, k);
    if (g == 0) {
        float dv = dinv[v];
        unsigned ws = sh[(size_t)v * D_H2 + (k >> 1)];
        __half2 ps = *(__half2*)&ws;
        float selfv = (k & 1) ? __high2float(ps) : __low2float(ps);
        float o = dv * (acc + selfv) + b2[k];
        h2[(size_t)v * D_H + k] = fmaxf(o, 0.f);
    }
}

// batch sorted: starts[g] = first node of graph g
__global__ void starts_kernel(const int* __restrict__ batch, int* __restrict__ starts) {
    int v = blockIdx.x * blockDim.x + threadIdx.x;
    if (v >= N_NODES) return;
    int bv = batch[v];
    int prev = (v == 0) ? -1 : batch[v - 1];
    for (int g = prev + 1; g <= bv; ++g) starts[g] = v;
    if (v == N_NODES - 1) {
        for (int g = bv + 1; g <= NUM_GRAPHS; ++g) starts[g] = N_NODES;
    }
}

// one block per graph: mean-pool h rows then sigmoid(pool @ Wl + bl)
__global__ void pool_head_kernel(const float* __restrict__ h, const int* __restrict__ starts,
                                 const float* __restrict__ Wl, const float* __restrict__ bl,
                                 float* __restrict__ out) {
    int g = blockIdx.x;
    int v0 = starts[g], v1 = starts[g + 1];
    int k = threadIdx.x & 15;
    int vi = threadIdx.x >> 4;
    float acc = 0.f;
    for (int v = v0 + vi; v < v1; v += 16) acc += h[v * D_H + k];
    acc += __shfl_xor(acc, 16, 64);
    acc += __shfl_xor(acc, 32, 64);
    __shared__ float sm[4][D_H];
    int lane = threadIdx.x & 63;
    if (lane < 16) sm[threadIdx.x >> 6][k] = acc;
    __syncthreads();
    if (threadIdx.x < 16) {
        float tot = sm[0][k] + sm[1][k] + sm[2][k] + sm[3][k];
        float cntf = (float)(v1 - v0);
        tot /= fmaxf(cntf, 1.0f);
        float p = tot * Wl[k];
        p += __shfl_xor(p, 1, 64);
        p += __shfl_xor(p, 2, 64);
        p += __shfl_xor(p, 4, 64);
        p += __shfl_xor(p, 8, 64);
        if (k == 0) out[g] = 1.0f / (1.0f + expf(-(p + bl[0])));
    }
}

// ---------------- launch ----------------

extern "C" void kernel_launch(void* const* d_in, const int* in_sizes, int n_in,
                              void* d_out, int out_size, void* d_ws, size_t ws_size,
                              hipStream_t stream) {
    const float* x     = (const float*)d_in[0];
    const int*   ei    = (const int*)d_in[1];   // [2, E]: row then col
    const int*   batch = (const int*)d_in[2];
    const float* W1    = (const float*)d_in[3];
    const float* b1    = (const float*)d_in[4];
    const float* W2    = (const float*)d_in[5];
    const float* b2    = (const float*)d_in[6];
    const float* Wl    = (const float*)d_in[7];
    const float* bl    = (const float*)d_in[8];
    float* out = (float*)d_out;

    const int* row = ei;
    const int* col = ei + N_EDGES;

    // workspace layout. Region A is time-shared: {cnt+base} then csr.
    char* wsb = (char*)d_ws;
    size_t o = 0;
    int*      part     = (int*)(wsb + o);      o += (size_t)N_EDGES * 4;      // 12.8 MB
    char*     regionA  = wsb + o;              o += (size_t)N_EDGES * 4;      // 12.8 MB
    int*      cnt      = (int*)regionA;                                       // [NCH][NB]
    int*      base     = (int*)(regionA + (size_t)NCH * NB * 4);              // [NB][NCH]
    int*      csr      = (int*)regionA;                                       // after place
    int*      bcnt     = (int*)(wsb + o);      o += 1024 * 4;
    int*      offs     = (int*)(wsb + o);      o += 1024 * 4;
    int*      node_off = (int*)(wsb + o);      o += 100352 * 4;
    int*      deg      = (int*)(wsb + o);      o += 100352 * 4;
    float*    dinv     = (float*)(wsb + o);    o += 100352 * 4;
    unsigned* sAh      = (unsigned*)(wsb + o); o += (size_t)N_NODES * D_H2 * 4; // 3.2 MB
    unsigned* sBh      = (unsigned*)(wsb + o); o += (size_t)N_NODES * D_H2 * 4; // 3.2 MB
    float*    h2       = (float*)(wsb + o);    o += (size_t)N_NODES * D_H * 4;  // 6.4 MB
    int*      starts   = (int*)(wsb + o);      o += 1024 * 4;

    const int B = 256;
    const int NVB = (N_NODES + B - 1) / B;   // 391

    // ---- build CSR via deterministic two-level scan (no global cursor atomics) ----
    hist_kernel<<<NCH, B, 0, stream>>>(col, cnt);
    colscan_kernel<<<NB, B, 0, stream>>>(cnt, base, bcnt);
    scan_kernel<<<1, 1024, 0, stream>>>(bcnt, offs);
    place_kernel<<<NCH, B, 0, stream>>>(row, col, base, offs, part);
    csr_kernel<<<NB, B, 0, stream>>>(part, offs, csr, node_off, deg, dinv);

    // ---- layer 1 (+ fused layer-2 GEMM) ----
    xw1_kernel<<<NVB, B, 0, stream>>>(x, W1, dinv, sAh);
    pull1_kernel<<<N_NODES / 4, B, 0, stream>>>(sAh, csr, node_off, deg, dinv,
                                                b1, W2, sBh);
    // ---- layer 2 ----
    pull2_kernel<<<N_NODES / 4, B, 0, stream>>>(sBh, csr, node_off, deg, dinv,
                                                b2, h2);
    // ---- pool + head ----
    starts_kernel<<<NVB, B, 0, stream>>>(batch, starts);
    pool_head_kernel<<<NUM_GRAPHS, B, 0, stream>>>(h2, starts, Wl, bl, out);
}

// Round 11
// 155.311 us; speedup vs baseline: 1.4480x; 1.0970x over previous
//
#include <hip/hip_runtime.h>
#include <hip/hip_fp16.h>
#include <math.h>

#define N_NODES    100000
#define N_EDGES    3200000
#define NUM_GRAPHS 512
#define D_IN       7
#define D_H        16
#define D_H2       8                           // half2 words per node row
#define SHIFT      7
#define BWIDTH     128                         // cols per bucket
#define NB         782                         // ceil(N_NODES / BWIDTH)
#define CHUNK      4096
#define NCH        782                         // ceil(N_EDGES / CHUNK)
#define PC         4                           // ceil(NCH / 256) chunks per thread (colscan)
#define PB         2                           // ceil(NB / 512) buckets per thread (place)
#define TPAD       68                          // padded words per staged feature-row

// ---- pass A: per-chunk bucket histograms ----
__global__ void hist_kernel(const int* __restrict__ col, int* __restrict__ cnt) {
    __shared__ int lh[NB];
    int tid = threadIdx.x;
    for (int i = tid; i < NB; i += blockDim.x) lh[i] = 0;
    __syncthreads();
    int e0 = blockIdx.x * CHUNK;
    int e1 = e0 + CHUNK; if (e1 > N_EDGES) e1 = N_EDGES;
    for (int e = e0 + tid; e < e1; e += blockDim.x)
        atomicAdd(&lh[col[e] >> SHIFT], 1);
    __syncthreads();
    int* outp = cnt + (size_t)blockIdx.x * NB;
    for (int i = tid; i < NB; i += blockDim.x) outp[i] = lh[i];
}

// ---- pass B: per-bucket exclusive scan over chunks ----
__global__ void colscan_kernel(const int* __restrict__ cnt, int* __restrict__ base,
                               int* __restrict__ bcnt) {
    __shared__ int ts[256];
    int b = blockIdx.x;
    int tid = threadIdx.x;
    int c0 = tid * PC;
    int vals[PC];
    int sum = 0;
#pragma unroll
    for (int q = 0; q < PC; ++q) {
        int c = c0 + q;
        int v = (c < NCH) ? cnt[(size_t)c * NB + b] : 0;
        vals[q] = v; sum += v;
    }
    ts[tid] = sum;
    __syncthreads();
    for (int st = 1; st < 256; st <<= 1) {
        int v = (tid >= st) ? ts[tid - st] : 0;
        __syncthreads();
        ts[tid] += v;
        __syncthreads();
    }
    int run = ts[tid] - sum;
    int* bp = base + (size_t)b * NCH;
#pragma unroll
    for (int q = 0; q < PC; ++q) {
        int c = c0 + q;
        if (c < NCH) { bp[c] = run; run += vals[q]; }
    }
    if (tid == 0) bcnt[b] = ts[255];
}

// ---- pass C: exclusive scan of bucket totals -> offs ----
__global__ void scan_kernel(const int* __restrict__ bcnt, int* __restrict__ offs) {
    __shared__ int lds[1024];
    int tid = threadIdx.x;
    lds[tid] = (tid < NB) ? bcnt[tid] : 0;
    __syncthreads();
    for (int st = 1; st < 1024; st <<= 1) {
        int v = (tid >= st) ? lds[tid - st] : 0;
        __syncthreads();
        lds[tid] += v;
        __syncthreads();
    }
    if (tid < NB) offs[tid + 1] = lds[tid];
    if (tid == 0) offs[0] = 0;
}

// ---- pass D: place (512 threads, CHUNK=4096) with LDS staging + precomputed
//      destinations + coalesced flush ----
__global__ void place_kernel(const int* __restrict__ row, const int* __restrict__ col,
                             const int* __restrict__ base, const int* __restrict__ offs,
                             int* __restrict__ part) {
    __shared__ int lh[NB];
    __shared__ int sc[NB];
    __shared__ int lb[NB];
    __shared__ int ts[512];
    __shared__ int stage[CHUNK];    // 16 KB
    __shared__ int dstv[CHUNK];     // 16 KB

    int c = blockIdx.x;
    int tid = threadIdx.x;
    int e0 = c * CHUNK;
    int e1 = e0 + CHUNK; if (e1 > N_EDGES) e1 = N_EDGES;
    int n  = e1 - e0;

    for (int i = tid; i < NB; i += blockDim.x) lh[i] = 0;
    __syncthreads();
    for (int e = e0 + tid; e < e1; e += blockDim.x)
        atomicAdd(&lh[col[e] >> SHIFT], 1);
    __syncthreads();
    int b0 = tid * PB;
    int vals[PB];
    int sum = 0;
#pragma unroll
    for (int q = 0; q < PB; ++q) {
        int b = b0 + q;
        int v = (b < NB) ? lh[b] : 0;
        vals[q] = v; sum += v;
    }
    ts[tid] = sum;
    __syncthreads();
    for (int st = 1; st < 512; st <<= 1) {
        int v = (tid >= st) ? ts[tid - st] : 0;
        __syncthreads();
        ts[tid] += v;
        __syncthreads();
    }
    int run = ts[tid] - sum;
#pragma unroll
    for (int q = 0; q < PB; ++q) {
        int b = b0 + q;
        if (b < NB) {
            sc[b] = run;
            lb[b] = offs[b] + base[(size_t)b * NCH + c];
            run += vals[q];
            lh[b] = 0;
        }
    }
    __syncthreads();
    for (int e = e0 + tid; e < e1; e += blockDim.x) {
        int cc = col[e];
        int b = cc >> SHIFT;
        int rank = atomicAdd(&lh[b], 1);
        int loc = sc[b] + rank;
        stage[loc] = (row[e] << SHIFT) | (cc & (BWIDTH - 1));
        dstv[loc]  = lb[b] + rank;
    }
    __syncthreads();
    for (int i = tid; i < n; i += blockDim.x)
        part[dstv[i]] = stage[i];
}

// ---- pass E: per-bucket CSR build + node_off/deg/dinv ----
__global__ void csr_kernel(const int* __restrict__ part, const int* __restrict__ offs,
                           int* __restrict__ csr, int* __restrict__ node_off,
                           int* __restrict__ deg, float* __restrict__ dinv) {
    __shared__ int cnt[BWIDTH];
    __shared__ int scn[BWIDTH];
    __shared__ int cur[BWIDTH];
    int b = blockIdx.x;
    int o0 = offs[b], o1 = offs[b + 1];
    if (threadIdx.x < BWIDTH) cnt[threadIdx.x] = 0;
    __syncthreads();
    for (int j = o0 + threadIdx.x; j < o1; j += blockDim.x)
        atomicAdd(&cnt[part[j] & (BWIDTH - 1)], 1);
    __syncthreads();
    if (threadIdx.x < BWIDTH) scn[threadIdx.x] = cnt[threadIdx.x];
    __syncthreads();
    for (int st = 1; st < BWIDTH; st <<= 1) {
        int v = 0;
        if (threadIdx.x < BWIDTH && threadIdx.x >= st) v = scn[threadIdx.x - st];
        __syncthreads();
        if (threadIdx.x < BWIDTH) scn[threadIdx.x] += v;
        __syncthreads();
    }
    if (threadIdx.x < BWIDTH) {
        int excl = scn[threadIdx.x] - cnt[threadIdx.x];
        cur[threadIdx.x] = excl;
        int c = b * BWIDTH + threadIdx.x;
        if (c < N_NODES) {
            node_off[c] = o0 + excl;
            deg[c] = cnt[threadIdx.x];
            dinv[c] = rsqrtf((float)cnt[threadIdx.x] + 1.0f);   // +1 self-loop
        }
    }
    __syncthreads();
    for (int j = o0 + threadIdx.x; j < o1; j += blockDim.x) {
        int e = part[j];
        int l = e & (BWIDTH - 1);
        int pos = atomicAdd(&cur[l], 1);
        csr[o0 + pos] = e >> SHIFT;
    }
}

// s[v,:] = dinv[v] * (x[v,:] @ W1), packed half2 (8 words/node)
__global__ void xw1_kernel(const float* __restrict__ x, const float* __restrict__ W1,
                           const float* __restrict__ dinv, unsigned* __restrict__ sh) {
    int v = blockIdx.x * blockDim.x + threadIdx.x;
    if (v >= N_NODES) return;
    float xv[D_IN];
#pragma unroll
    for (int j = 0; j < D_IN; ++j) xv[j] = x[v * D_IN + j];
    float dv = dinv[v];
#pragma unroll
    for (int k2 = 0; k2 < D_H2; ++k2) {
        float a0 = 0.f, a1 = 0.f;
#pragma unroll
        for (int j = 0; j < D_IN; ++j) {
            a0 += xv[j] * W1[j * D_H + 2 * k2];
            a1 += xv[j] * W1[j * D_H + 2 * k2 + 1];
        }
        __half2 p = __floats2half2_rn(a0 * dv, a1 * dv);
        sh[v * D_H2 + k2] = *(unsigned*)&p;
    }
}

// ---- shared gather core: lane-per-edge, transposed LDS staging.
// st layout: st[w * TPAD + j] = word w of edge-slot j (w=0..7, j=0..63).
// Writes: 8 coalesced b32 per lane. Reads: lane (g,k) sums rows g*16..g*16+15 of
// word (k>>1) via 4 x ds_read_b128 (2-way aliased + broadcast = conflict-free).
__device__ __forceinline__ float gather_sum(const unsigned* __restrict__ sh,
                                            const int* __restrict__ csr,
                                            int o0, int d, unsigned* st,
                                            int lane, int g, int k) {
    float acc = 0.f;
    int w = k >> 1;
    bool hi = (k & 1);
    const uint4* rp = (const uint4*)(st + w * TPAD + g * 16);
    for (int base = 0; base < d; base += 64) {
        int j = base + lane;
        uint4 a = make_uint4(0u, 0u, 0u, 0u), b = make_uint4(0u, 0u, 0u, 0u);
        if (j < d) {
            int r = csr[o0 + j];
            const uint4* p = (const uint4*)(sh + (size_t)r * D_H2);
            a = p[0];
            b = p[1];
        }
        // previous pass's reads fully drained before overwriting the stage
        asm volatile("s_waitcnt lgkmcnt(0)" ::: "memory");
        st[0 * TPAD + lane] = a.x;
        st[1 * TPAD + lane] = a.y;
        st[2 * TPAD + lane] = a.z;
        st[3 * TPAD + lane] = a.w;
        st[4 * TPAD + lane] = b.x;
        st[5 * TPAD + lane] = b.y;
        st[6 * TPAD + lane] = b.z;
        st[7 * TPAD + lane] = b.w;
        asm volatile("s_waitcnt lgkmcnt(0)" ::: "memory");
        uint4 q0 = rp[0], q1 = rp[1], q2 = rp[2], q3 = rp[3];
        unsigned ws[16] = { q0.x, q0.y, q0.z, q0.w, q1.x, q1.y, q1.z, q1.w,
                            q2.x, q2.y, q2.z, q2.w, q3.x, q3.y, q3.z, q3.w };
#pragma unroll
        for (int i = 0; i < 16; ++i) {
            __half2 p = *(__half2*)&ws[i];
            acc += hi ? __high2float(p) : __low2float(p);
        }
    }
    acc += __shfl_xor(acc, 16, 64);
    acc += __shfl_xor(acc, 32, 64);
    return acc;
}

// layer-1 pull + fused @W2 epilogue (LDS-broadcast h-row)
__global__ void __launch_bounds__(256, 8)
pull1_kernel(const unsigned* __restrict__ sh, const int* __restrict__ csr,
             const int* __restrict__ node_off, const int* __restrict__ deg,
             const float* __restrict__ dinv, const float* __restrict__ b1,
             const float* __restrict__ W2, unsigned* __restrict__ s2h) {
    __shared__ unsigned stage[4][8 * TPAD];       // 8704 B
    __shared__ float hrow[4][D_H];
    int wave = threadIdx.x >> 6;
    int v = blockIdx.x * 4 + wave;
    int lane = threadIdx.x & 63;
    int g = lane >> 4, k = lane & 15;
    float w2c[D_H];
#pragma unroll
    for (int j = 0; j < D_H; ++j) w2c[j] = W2[j * D_H + k];
    int d = deg[v], o0 = node_off[v];
    float acc = gather_sum(sh, csr, o0, d, stage[wave], lane, g, k);
    float dv = dinv[v];
    unsigned ws = sh[(size_t)v * D_H2 + (k >> 1)];
    __half2 ps = *(__half2*)&ws;
    float selfv = (k & 1) ? __high2float(ps) : __low2float(ps);
    float h = fmaxf(dv * (acc + selfv) + b1[k], 0.f);
    if (g == 0) hrow[wave][k] = h;
    asm volatile("s_waitcnt lgkmcnt(0)" ::: "memory");
    const float4* hp = (const float4*)hrow[wave];
    float4 h0 = hp[0], h1 = hp[1], h2 = hp[2], h3 = hp[3];
    float a2 = h0.x * w2c[0] + h0.y * w2c[1] + h0.z * w2c[2] + h0.w * w2c[3]
             + h1.x * w2c[4] + h1.y * w2c[5] + h1.z * w2c[6] + h1.w * w2c[7]
             + h2.x * w2c[8] + h2.y * w2c[9] + h2.z * w2c[10] + h2.w * w2c[11]
             + h3.x * w2c[12] + h3.y * w2c[13] + h3.z * w2c[14] + h3.w * w2c[15];
    a2 *= dv;
    float a2hi = __shfl_xor(a2, 1, 64);
    if (g == 0 && (k & 1) == 0) {
        __half2 p = __floats2half2_rn(a2, a2hi);
        s2h[(size_t)v * D_H2 + (k >> 1)] = *(unsigned*)&p;
    }
}

// layer-2 pull: h2 = relu(dinv*(gather+self)+b2), fp32 out
__global__ void __launch_bounds__(256, 8)
pull2_kernel(const unsigned* __restrict__ sh, const int* __restrict__ csr,
             const int* __restrict__ node_off, const int* __restrict__ deg,
             const float* __restrict__ dinv, const float* __restrict__ b2,
             float* __restrict__ h2) {
    __shared__ unsigned stage[4][8 * TPAD];
    int wave = threadIdx.x >> 6;
    int v = blockIdx.x * 4 + wave;
    int lane = threadIdx.x & 63;
    int g = lane >> 4, k = lane & 15;
    int d = deg[v], o0 = node_off[v];
    float acc = gather_sum(sh, csr, o0, d, stage[wave], lane, g, k);
    if (g == 0) {
        float dv = dinv[v];
        unsigned ws = sh[(size_t)v * D_H2 + (k >> 1)];
        __half2 ps = *(__half2*)&ws;
        float selfv = (k & 1) ? __high2float(ps) : __low2float(ps);
        float o = dv * (acc + selfv) + b2[k];
        h2[(size_t)v * D_H + k] = fmaxf(o, 0.f);
    }
}

// batch sorted: starts[g] = first node of graph g
__global__ void starts_kernel(const int* __restrict__ batch, int* __restrict__ starts) {
    int v = blockIdx.x * blockDim.x + threadIdx.x;
    if (v >= N_NODES) return;
    int bv = batch[v];
    int prev = (v == 0) ? -1 : batch[v - 1];
    for (int g = prev + 1; g <= bv; ++g) starts[g] = v;
    if (v == N_NODES - 1) {
        for (int g = bv + 1; g <= NUM_GRAPHS; ++g) starts[g] = N_NODES;
    }
}

// one block per graph: mean-pool h rows then sigmoid(pool @ Wl + bl)
__global__ void pool_head_kernel(const float* __restrict__ h, const int* __restrict__ starts,
                                 const float* __restrict__ Wl, const float* __restrict__ bl,
                                 float* __restrict__ out) {
    int g = blockIdx.x;
    int v0 = starts[g], v1 = starts[g + 1];
    int k = threadIdx.x & 15;
    int vi = threadIdx.x >> 4;
    float acc = 0.f;
    for (int v = v0 + vi; v < v1; v += 16) acc += h[v * D_H + k];
    acc += __shfl_xor(acc, 16, 64);
    acc += __shfl_xor(acc, 32, 64);
    __shared__ float sm[4][D_H];
    int lane = threadIdx.x & 63;
    if (lane < 16) sm[threadIdx.x >> 6][k] = acc;
    __syncthreads();
    if (threadIdx.x < 16) {
        float tot = sm[0][k] + sm[1][k] + sm[2][k] + sm[3][k];
        float cntf = (float)(v1 - v0);
        tot /= fmaxf(cntf, 1.0f);
        float p = tot * Wl[k];
        p += __shfl_xor(p, 1, 64);
        p += __shfl_xor(p, 2, 64);
        p += __shfl_xor(p, 4, 64);
        p += __shfl_xor(p, 8, 64);
        if (k == 0) out[g] = 1.0f / (1.0f + expf(-(p + bl[0])));
    }
}

// ---------------- launch ----------------

extern "C" void kernel_launch(void* const* d_in, const int* in_sizes, int n_in,
                              void* d_out, int out_size, void* d_ws, size_t ws_size,
                              hipStream_t stream) {
    const float* x     = (const float*)d_in[0];
    const int*   ei    = (const int*)d_in[1];   // [2, E]: row then col
    const int*   batch = (const int*)d_in[2];
    const float* W1    = (const float*)d_in[3];
    const float* b1    = (const float*)d_in[4];
    const float* W2    = (const float*)d_in[5];
    const float* b2    = (const float*)d_in[6];
    const float* Wl    = (const float*)d_in[7];
    const float* bl    = (const float*)d_in[8];
    float* out = (float*)d_out;

    const int* row = ei;
    const int* col = ei + N_EDGES;

    // workspace layout. Region A is time-shared: {cnt+base} then csr.
    char* wsb = (char*)d_ws;
    size_t o = 0;
    int*      part     = (int*)(wsb + o);      o += (size_t)N_EDGES * 4;      // 12.8 MB
    char*     regionA  = wsb + o;              o += (size_t)N_EDGES * 4;      // 12.8 MB
    int*      cnt      = (int*)regionA;                                       // [NCH][NB]
    int*      base     = (int*)(regionA + (size_t)NCH * NB * 4);              // [NB][NCH]
    int*      csr      = (int*)regionA;                                       // after place
    int*      bcnt     = (int*)(wsb + o);      o += 1024 * 4;
    int*      offs     = (int*)(wsb + o);      o += 1024 * 4;
    int*      node_off = (int*)(wsb + o);      o += 100352 * 4;
    int*      deg      = (int*)(wsb + o);      o += 100352 * 4;
    float*    dinv     = (float*)(wsb + o);    o += 100352 * 4;
    unsigned* sAh      = (unsigned*)(wsb + o); o += (size_t)N_NODES * D_H2 * 4; // 3.2 MB
    unsigned* sBh      = (unsigned*)(wsb + o); o += (size_t)N_NODES * D_H2 * 4; // 3.2 MB
    float*    h2       = (float*)(wsb + o);    o += (size_t)N_NODES * D_H * 4;  // 6.4 MB
    int*      starts   = (int*)(wsb + o);      o += 1024 * 4;

    const int B = 256;
    const int NVB = (N_NODES + B - 1) / B;   // 391

    // ---- build CSR via deterministic two-level scan (no global cursor atomics) ----
    hist_kernel<<<NCH, B, 0, stream>>>(col, cnt);
    colscan_kernel<<<NB, B, 0, stream>>>(cnt, base, bcnt);
    scan_kernel<<<1, 1024, 0, stream>>>(bcnt, offs);
    place_kernel<<<NCH, 512, 0, stream>>>(row, col, base, offs, part);
    csr_kernel<<<NB, B, 0, stream>>>(part, offs, csr, node_off, deg, dinv);

    // ---- layer 1 (+ fused layer-2 GEMM) ----
    xw1_kernel<<<NVB, B, 0, stream>>>(x, W1, dinv, sAh);
    pull1_kernel<<<N_NODES / 4, B, 0, stream>>>(sAh, csr, node_off, deg, dinv,
                                                b1, W2, sBh);
    // ---- layer 2 ----
    pull2_kernel<<<N_NODES / 4, B, 0, stream>>>(sBh, csr, node_off, deg, dinv,
                                                b2, h2);
    // ---- pool + head ----
    starts_kernel<<<NVB, B, 0, stream>>>(batch, starts);
    pool_head_kernel<<<NUM_GRAPHS, B, 0, stream>>>(h2, starts, Wl, bl, out);
}